// Round 2
// baseline (2680.453 us; speedup 1.0000x reference)
//
#include <hip/hip_runtime.h>
#include <math.h>

#define NATOMS 100000
#define M 12
#define A 64
#define F 41
#define FP 44     // padded weight row length (16B multiple)
#define C1 128    // 2A
#define TOTF 169  // 2A+F
#define NMROWS (NATOMS * M)

// ---- workspace layout (float offsets) ----
#define OFF_WEFF 0                      // W_eff transposed [3][128][44] = 16896
#define OFF_BEFF 16896                  // [3][128] = 384
#define OFF_SUM1 17280                  // [384]
#define OFF_SQ1  17664                  // [384]
#define OFF_SUM2 18048                  // [192]
#define OFF_SQ2  18240                  // [192]  (SUM1..SQ2 = 1152 floats, zeroed)
#define OFF_SCA  18432                  // [384]
#define OFF_SHA  18816                  // [384]
#define OFF_SCB  19200                  // [192]
#define OFF_SHB  19392                  // [192]
#define OFF_P    32768                  // P_all [N][768]
#define OFF_SUMMED (OFF_P + (size_t)NATOMS*768)  // [3][N][64]
#define OFF_Q    OFF_P                  // q [N][192] overlays dead P

__device__ __forceinline__ float sigmoidf_(float x) {
    return 1.0f / (1.0f + __expf(-x));
}
__device__ __forceinline__ float softplusf_(float x) {
    return fmaxf(x, 0.0f) + __logf(1.0f + __expf(-fabsf(x)));
}

// K0: W_eff (transposed, padded) and b_eff.
// W_eff[s][k][col] = (s==0 ? Wf[128+k][col] : sum_q Wsc[s-1][k][q] * Wf[128+q][col])
// stored at ws[OFF_WEFF + (s*128+col)*FP + k]
__global__ void k_weff(const float* __restrict__ Wf, const float* __restrict__ bf,
                       const float* __restrict__ Wsc, const float* __restrict__ bsc,
                       float* __restrict__ ws) {
    int j = threadIdx.x;  // 128 = column within scale
    float* We = ws + OFF_WEFF;
    float* be = ws + OFF_BEFF;
    for (int s = 0; s < 3; ++s) {
        float bb = bf[s * C1 + j];
        if (s > 0) {
            for (int q = 0; q < F; ++q)
                bb += bsc[(s - 1) * F + q] * Wf[(s * TOTF + 128 + q) * C1 + j];
        }
        be[s * C1 + j] = bb;
        float* dst = We + (size_t)(s * 128 + j) * FP;
        for (int k = 0; k < F; ++k) {
            float v;
            if (s == 0) {
                v = Wf[(0 * TOTF + 128 + k) * C1 + j];
            } else {
                v = 0.0f;
                for (int q = 0; q < F; ++q)
                    v += Wsc[((s - 1) * F + k) * F + q] * Wf[(s * TOTF + 128 + q) * C1 + j];
            }
            dst[k] = v;
        }
        for (int k = F; k < FP; ++k) dst[k] = 0.0f;
    }
}

// K1: P precompute, interleaved layout.
// slot u (0..255) within scale s:
//   u <  128: SELF part, j=u>>1, role=u&1 -> W rows 0..63,  W col = role*64 + j
//   u >= 128: NBR  part, v=u-128, j=v>>1, role=v&1 -> W rows 64..127, W col = role*64 + j
__global__ __launch_bounds__(256, 4) void k_pall(const float* __restrict__ atom,
                                                 const float* __restrict__ Wf,
                                                 float* __restrict__ ws) {
    int u = threadIdx.x;
    int s = blockIdx.x;  // 0..2
    int v = u & 127;
    int part = u >> 7;            // 0 self, 1 nbr
    int j = v >> 1;
    int role = v & 1;
    int col = role * 64 + j;
    int rowbase = part * 64;
    float wcol[A];
#pragma unroll
    for (int k = 0; k < A; ++k)
        wcol[k] = Wf[(s * TOTF + rowbase + k) * C1 + col];
    float* P = ws + OFF_P;
#pragma unroll 1
    for (int a = blockIdx.y; a < NATOMS; a += gridDim.y) {
        const float4* ar4 = (const float4*)(atom + (size_t)a * A);  // 256B-aligned, uniform
        float acc = 0.0f;
#pragma unroll
        for (int t = 0; t < 16; ++t) {
            float4 av = ar4[t];
            acc = fmaf(av.x, wcol[4 * t + 0], acc);
            acc = fmaf(av.y, wcol[4 * t + 1], acc);
            acc = fmaf(av.z, wcol[4 * t + 2], acc);
            acc = fmaf(av.w, wcol[4 * t + 3], acc);
        }
        P[(size_t)a * 768 + s * 256 + u] = acc;
    }
}

// K2 (PASS=0): z stats.  K4 (PASS=1): apply BN1, activation, sum over m, BN2 stats.
// block = 192 threads = 3 waves; wave = scale s; lane j owns columns j (filt), j+64 (core).
template <int PASS>
__global__ __launch_bounds__(192, 4) void k_conv(const float* __restrict__ nbr,
                                                 const int* __restrict__ idx,
                                                 float* __restrict__ ws) {
    int tid = threadIdx.x;
    int s = tid >> 6;
    int j = tid & 63;
    const float* P = ws + OFF_P;

    // weights: one-time 16B-aligned per-lane vector loads, statically indexed
    const float4* wt1 = (const float4*)(ws + OFF_WEFF + (size_t)(s * 128 + j) * FP);
    const float4* wt2 = (const float4*)(ws + OFF_WEFF + (size_t)(s * 128 + 64 + j) * FP);
    float4 w1v[11], w2v[11];
#pragma unroll
    for (int t = 0; t < 11; ++t) { w1v[t] = wt1[t]; w2v[t] = wt2[t]; }

    float b1 = ws[OFF_BEFF + s * C1 + j];
    float b2 = ws[OFF_BEFF + s * C1 + 64 + j];
    float sc1 = 0.f, sh1 = 0.f, sc2 = 0.f, sh2 = 0.f;
    if (PASS == 1) {
        sc1 = ws[OFF_SCA + s * C1 + j];
        sh1 = ws[OFF_SHA + s * C1 + j];
        sc2 = ws[OFF_SCA + s * C1 + 64 + j];
        sh2 = ws[OFF_SHA + s * C1 + 64 + j];
    }
    float accA = 0.f, accB = 0.f, accC = 0.f, accD = 0.f;
    float* summed = ws + OFF_SUMMED;

#pragma unroll 1
    for (int a = blockIdx.x; a < NATOMS; a += gridDim.x) {
        const float2 ps = *(const float2*)(P + (size_t)a * 768 + s * 256 + 2 * j);
        float hsum = 0.0f;
#pragma unroll 1
        for (int m = 0; m < M; ++m) {
            int pair = a * M + m;
            int row = idx[pair];                      // wave-uniform
            const float* x = nbr + (size_t)pair * F;  // wave-uniform
            const float2 gn = *(const float2*)(P + (size_t)row * 768 + s * 256 + 128 + 2 * j);
            float z1 = b1 + ps.x + gn.x;
            float z2 = b2 + ps.y + gn.y;
#pragma unroll
            for (int t = 0; t < 10; ++t) {
                float x0 = x[4 * t + 0], x1 = x[4 * t + 1], x2 = x[4 * t + 2], x3 = x[4 * t + 3];
                z1 = fmaf(x0, w1v[t].x, z1);
                z2 = fmaf(x0, w2v[t].x, z2);
                z1 = fmaf(x1, w1v[t].y, z1);
                z2 = fmaf(x1, w2v[t].y, z2);
                z1 = fmaf(x2, w1v[t].z, z1);
                z2 = fmaf(x2, w2v[t].z, z2);
                z1 = fmaf(x3, w1v[t].w, z1);
                z2 = fmaf(x3, w2v[t].w, z2);
            }
            float x40 = x[40];
            z1 = fmaf(x40, w1v[10].x, z1);
            z2 = fmaf(x40, w2v[10].x, z2);
            if (PASS == 0) {
                accA += z1; accB = fmaf(z1, z1, accB);
                accC += z2; accD = fmaf(z2, z2, accD);
            } else {
                float f = fmaf(z1, sc1, sh1);
                float c = fmaf(z2, sc2, sh2);
                hsum = fmaf(sigmoidf_(f), softplusf_(c), hsum);
            }
        }
        if (PASS == 1) {
            summed[((size_t)s * NATOMS + a) * 64 + j] = hsum;
            accA += hsum;
            accB = fmaf(hsum, hsum, accB);
        }
    }
    if (PASS == 0) {
        atomicAdd(&ws[OFF_SUM1 + s * C1 + j], accA);
        atomicAdd(&ws[OFF_SQ1 + s * C1 + j], accB);
        atomicAdd(&ws[OFF_SUM1 + s * C1 + 64 + j], accC);
        atomicAdd(&ws[OFF_SQ1 + s * C1 + 64 + j], accD);
    } else {
        atomicAdd(&ws[OFF_SUM2 + s * 64 + j], accA);
        atomicAdd(&ws[OFF_SQ2 + s * 64 + j], accB);
    }
}

// K3: BN1 params
__global__ void k_bn1(const float* __restrict__ g1, const float* __restrict__ bt1,
                      float* __restrict__ ws) {
    int c = threadIdx.x;  // 384
    float inv = 1.0f / (float)NMROWS;
    float mu = ws[OFF_SUM1 + c] * inv;
    float var = ws[OFF_SQ1 + c] * inv - mu * mu;
    float rs = rsqrtf(var + 1e-5f);
    float g = g1[c];
    ws[OFF_SCA + c] = g * rs;
    ws[OFF_SHA + c] = bt1[c] - mu * rs * g;
}

// K5: BN2 params
__global__ void k_bn2(const float* __restrict__ g2, const float* __restrict__ bt2,
                      float* __restrict__ ws) {
    int c = threadIdx.x;  // 192
    float inv = 1.0f / (float)NATOMS;
    float mu = ws[OFF_SUM2 + c] * inv;
    float var = ws[OFF_SQ2 + c] * inv - mu * mu;
    float rs = rsqrtf(var + 1e-5f);
    float g = g2[c];
    ws[OFF_SCB + c] = g * rs;
    ws[OFF_SHB + c] = bt2[c] - mu * rs * g;
}

// K5b: q[a][s*64+j] = softplus(atom_fea[a][j] + bn2(summed))
__global__ __launch_bounds__(256) void k_q(const float* __restrict__ atom,
                                           float* __restrict__ ws) {
    size_t e = (size_t)blockIdx.x * 256 + threadIdx.x;
    if (e >= (size_t)NATOMS * 192) return;
    int a = (int)(e / 192);
    int c = (int)(e % 192);
    int s = c >> 6;
    int j = c & 63;
    float v = ws[OFF_SUMMED + ((size_t)s * NATOMS + a) * 64 + j];
    v = fmaf(v, ws[OFF_SCB + c], ws[OFF_SHB + c]);
    v += atom[(size_t)a * A + j];
    ws[OFF_Q + (size_t)a * 192 + c] = softplusf_(v);
}

// K6: out = relu(q @ W_fuse + b_fuse).  2-wave split-K: wave w covers k in [w*96, w*96+96),
// lane o = output column; batches of 8 atoms; LDS combine (double-buffered).
__global__ __launch_bounds__(128, 3) void k_fuse(const float* __restrict__ Wfu,
                                                 const float* __restrict__ bfu,
                                                 const float* __restrict__ ws,
                                                 float* __restrict__ out) {
    int w = threadIdx.x >> 6;
    int o = threadIdx.x & 63;
    __shared__ float sp[2][8][64];
    float4 wv[24];
#pragma unroll
    for (int t = 0; t < 24; ++t) {
        int k = w * 96 + 4 * t;
        wv[t].x = Wfu[(k + 0) * 64 + o];  // coalesced across lanes per k
        wv[t].y = Wfu[(k + 1) * 64 + o];
        wv[t].z = Wfu[(k + 2) * 64 + o];
        wv[t].w = Wfu[(k + 3) * 64 + o];
    }
    float bb = bfu[o];
    const float* q = ws + OFF_Q;
    int p = 0;
#pragma unroll 1
    for (int cid = blockIdx.x; cid < NATOMS / 8; cid += gridDim.x) {
        float acc[8];
#pragma unroll
        for (int i = 0; i < 8; ++i) {
            // q row 16B-aligned: (a*192 + w*96)*4 is a multiple of 16
            const float4* q4 = (const float4*)(q + (size_t)(cid * 8 + i) * 192 + w * 96);
            float a0 = 0.f, a1 = 0.f, a2 = 0.f, a3 = 0.f;
#pragma unroll
            for (int t = 0; t < 24; ++t) {
                float4 xq = q4[t];
                a0 = fmaf(xq.x, wv[t].x, a0);
                a1 = fmaf(xq.y, wv[t].y, a1);
                a2 = fmaf(xq.z, wv[t].z, a2);
                a3 = fmaf(xq.w, wv[t].w, a3);
            }
            acc[i] = (a0 + a1) + (a2 + a3);
        }
        if (w == 1) {
#pragma unroll
            for (int i = 0; i < 8; ++i) sp[p][i][o] = acc[i];
        }
        __syncthreads();
        if (w == 0) {
#pragma unroll
            for (int i = 0; i < 8; ++i)
                out[(size_t)(cid * 8 + i) * 64 + o] = fmaxf(acc[i] + sp[p][i][o] + bb, 0.0f);
        }
        p ^= 1;
    }
}

extern "C" void kernel_launch(void* const* d_in, const int* in_sizes, int n_in,
                              void* d_out, int out_size, void* d_ws, size_t ws_size,
                              hipStream_t stream) {
    const float* atom = (const float*)d_in[0];   // [N,64]
    const float* nbr  = (const float*)d_in[1];   // [N,12,41]
    const int*   idx  = (const int*)d_in[2];     // [N,12]
    const float* Wf   = (const float*)d_in[3];   // [3,169,128]
    const float* bf   = (const float*)d_in[4];   // [3,128]
    const float* g1   = (const float*)d_in[5];   // [3,128]
    const float* bt1  = (const float*)d_in[6];   // [3,128]
    const float* g2   = (const float*)d_in[7];   // [3,64]
    const float* bt2  = (const float*)d_in[8];   // [3,64]
    const float* Wsc  = (const float*)d_in[9];   // [2,41,41]
    const float* bsc  = (const float*)d_in[10];  // [2,41]
    const float* Wfu  = (const float*)d_in[11];  // [192,64]
    const float* bfu  = (const float*)d_in[12];  // [64]
    float* out = (float*)d_out;
    float* ws = (float*)d_ws;

    hipMemsetAsync((char*)d_ws + OFF_SUM1 * sizeof(float), 0, 1152 * sizeof(float), stream);

    k_weff<<<1, 128, 0, stream>>>(Wf, bf, Wsc, bsc, ws);
    k_pall<<<dim3(3, 512), 256, 0, stream>>>(atom, Wf, ws);
    k_conv<0><<<1280, 192, 0, stream>>>(nbr, idx, ws);
    k_bn1<<<1, 384, 0, stream>>>(g1, bt1, ws);
    k_conv<1><<<1280, 192, 0, stream>>>(nbr, idx, ws);
    k_bn2<<<1, 192, 0, stream>>>(g2, bt2, ws);
    k_q<<<(NATOMS * 192 + 255) / 256, 256, 0, stream>>>(atom, ws);
    k_fuse<<<2048, 128, 0, stream>>>(Wfu, bfu, ws, out);
}